// Round 8
// baseline (1001.910 us; speedup 1.0000x reference)
//
#include <hip/hip_runtime.h>

typedef _Float16 f16;
typedef _Float16 f16x4 __attribute__((ext_vector_type(4)));
typedef _Float16 f16x8 __attribute__((ext_vector_type(8)));
typedef float f32x4 __attribute__((ext_vector_type(4)));

#define MFMA16(a, b, c) __builtin_amdgcn_mfma_f32_16x16x32_f16((a), (b), (c), 0, 0, 0)

__device__ __forceinline__ float rcp_(float x) { return __builtin_amdgcn_rcpf(x); }
__device__ __forceinline__ float sigm(float v) { return rcp_(1.0f + __expf(-v)); }
__device__ __forceinline__ float tanh_(float v) { return 1.0f - 2.0f * rcp_(__expf(2.0f * v) + 1.0f); }

// ============ Kernel A: persistent ConvLSTM recurrence (R8) ====================
// Grid 512 (2 blocks/CU), 16 groups of 4 samples per block, 256 thr = 4 waves =
// mg(0..1) x ng(0..1); wave tile M=64 x N=32; all 9 tap A-frags in registers.
// R8 changes vs R7:
//  (a) hpad is k-group-major [buf][b][kg][cell][16B]: B-frag ds_read_b128 hits
//      every bank exactly 8x (bank = lk*16 + cell*4 mod 32) -> ~0 read conflicts.
//  (b) hpad/xpad double-buffered: reads from buf(t&1), h' writes to buf(~t&1),
//      ONE __syncthreads per t-step (was 2) -> phase overlap across waves.
//
// LDS: hpad [2 buf][4 b][4 kg][36 cell][16B]  0..18432     (buf 9216, b 2304, kg 576)
//      xpad [2 buf][4 b][36 cell][4 sl f16]   18432..20736 (buf 1152, b 288, cell 8)
//      WS prologue scratch                    20736..39168
#define XP 18432
#define WSO 20736
#define SMEMA 39168
#define NGRP 8192
#define GRID_REC 512

extern "C" __global__ __launch_bounds__(256, 2)
void hwq_rec(const float* __restrict__ gx, const float* __restrict__ ghour,
             const float* __restrict__ gcw, const float* __restrict__ gcb,
             const float* __restrict__ ghw1, const float* __restrict__ ghb1,
             const float* __restrict__ ghw2, const float* __restrict__ ghb2,
             f16* __restrict__ wz)
{
  __shared__ __align__(16) char smem[SMEMA];
  const int tid = threadIdx.x;
  const int lane = tid & 63;
  const int wv = tid >> 6;
  const int mg = wv & 1;                // M-half: m in [mg*64, mg*64+64)
  const int ng = wv >> 1;               // N-half: samples ng*2, ng*2+1
  const int lr = lane & 15;
  const int lk = lane >> 4;
  const int TOFF[9] = {0, 1, 2, 6, 7, 8, 12, 13, 14};
  const int pp0 = (lr >> 2) * 6 + (lr & 3);

  // ---- prologue 1: zero hpad(both bufs)+xpad(both); stage Ax1 [128 m][32 k] ----
  {
    float* za = (float*)smem;
    for (int i = tid; i < 5184; i += 256) za[i] = 0.0f;
    f16* axs = (f16*)(smem + WSO);
    for (int i = tid; i < 4096; i += 256) {
      int m = i >> 5, k = i & 31;
      int tau = k >> 2, sl = k & 3;
      int oc = ((m & 3) << 5) + (m >> 2);
      f16 v = (f16)0.0f;
      if (sl < 3) v = (f16)gcw[oc * 315 + sl * 9 + tau];
      else if (tau == 4) v = (f16)gcb[oc];
      axs[i] = v;
    }
    __syncthreads();
  }
  // ---- prologue 2: xpad bias flags (both bufs); gather Ax1; Ax2 (tap 8) ----
  f16x8 Ax1[4], Ax2[4];
  {
    if (tid < 128) {
      int buf = tid >> 6, b = (tid >> 4) & 3, p = tid & 15;
      int cell = ((p >> 2) + 1) * 6 + (p & 3) + 1;
      *(f16*)(smem + XP + buf * 1152 + b * 288 + cell * 8 + 6) = (f16)1.0f;
    }
    #pragma unroll
    for (int mt = 0; mt < 4; ++mt) {
      Ax1[mt] = *(const f16x8*)(smem + WSO + (mg * 64 + mt * 16 + lr) * 64 + lk * 16);
      int m = mg * 64 + mt * 16 + lr;
      int oc = ((m & 3) << 5) + (m >> 2);
      f16x8 f = {(f16)0, (f16)0, (f16)0, (f16)0, (f16)0, (f16)0, (f16)0, (f16)0};
      if (lk == 0) {
        f[0] = (f16)gcw[oc * 315 + 8];
        f[1] = (f16)gcw[oc * 315 + 17];
        f[2] = (f16)gcw[oc * 315 + 26];
      }
      Ax2[mt] = f;
    }
    __syncthreads();
  }
  // ---- prologue 3: ALL 9 tap A-frags via 4 staged chunks of 32 m-rows ----
  f16x8 Ah[9][4];
  {
    f16* wst = (f16*)(smem + WSO);   // [32 row][288 = ch*9+tap]
    #pragma unroll
    for (int c = 0; c < 4; ++c) {
      for (int i = tid; i < 9216; i += 256) {
        int mrow = i / 288, rem = i - mrow * 288;
        int m = c * 32 + mrow;
        int oc = ((m & 3) << 5) + (m >> 2);
        wst[i] = (f16)gcw[oc * 315 + 27 + rem];
      }
      __syncthreads();
      if (mg == (c >> 1)) {
        #pragma unroll
        for (int mtl = 0; mtl < 2; ++mtl) {
          int mt = (c & 1) * 2 + mtl;
          #pragma unroll
          for (int tap = 0; tap < 9; ++tap) {
            f16x8 f;
            #pragma unroll
            for (int j = 0; j < 8; ++j)
              f[j] = wst[(mtl * 16 + lr) * 288 + (lk * 8 + j) * 9 + tap];
            Ah[tap][mt] = f;
          }
        }
      }
      __syncthreads();
    }
  }

  // ---- hot-loop bases (group-invariant) ----
  const int hb  = (ng * 2) * 2304 + lk * 576 + pp0 * 16;   // B-read: +rb*9216 +nt*2304 +toff*16
  const int xpb = (ng * 2) * 288 + pp0 * 8;                // x-read: +XP +rb*1152 +nt*288
  // h' write: + (rb^1)*9216 + nt*2304 + (mt>>1)*576 + (mt&1)*8
  const int wbase = (ng * 2) * 2304 + (mg * 2) * 576 + (pp0 + 7) * 16 + lk * 2;
  const int xo0 = TOFF[2 * lk] * 8;
  const int xo1 = TOFF[2 * lk + 1] * 8;
  const bool stg = tid < 192;
  const int sb = tid / 48, srem = tid - sb * 48;
  const int sp = srem & 15, sic = srem >> 4;
  const int xdst = XP + sb * 288 + (((sp >> 2) + 1) * 6 + (sp & 3) + 1) * 8 + sic * 2;
  // group-start zero of hbuf0 interior: one b128 per thread
  const int zb_ = tid >> 6, zkg = (tid >> 4) & 3, zc = tid & 15;
  const int zaddr = zb_ * 2304 + zkg * 576 + (((zc >> 2) + 1) * 6 + (zc & 3) + 1) * 16;

  for (int grp = blockIdx.x; grp < NGRP; grp += GRID_REC) {
    const int bg = grp << 2;
    const float* gxb = gx + (size_t)bg * 576;
    const float* xsrc = gxb + (size_t)sb * 576 + srem;

    // group re-init: zero hbuf0 interior (h0 = 0), stage xpad(t=0) into xbuf0
    {
      f32x4 z4 = {0.f, 0.f, 0.f, 0.f};
      *(f32x4*)(smem + zaddr) = z4;
    }
    if (stg) *(f16*)(smem + xdst) = (f16)xsrc[0];
    float cst[4][2];
    #pragma unroll
    for (int mt = 0; mt < 4; ++mt) { cst[mt][0] = 0.0f; cst[mt][1] = 0.0f; }
    __syncthreads();

#define STEP(T, RB)                                                              \
    {                                                                            \
      const int t = (T);                                                         \
      float xv = 0.0f;                                                           \
      if (t < 11 && stg) xv = xsrc[(t + 1) * 48];                                \
      f32x4 acc[4][2];                                                           \
      _Pragma("unroll")                                                          \
      for (int mt = 0; mt < 4; ++mt) {                                           \
        f32x4 z = {0.f, 0.f, 0.f, 0.f};                                          \
        acc[mt][0] = z; acc[mt][1] = z;                                          \
      }                                                                          \
      const char* hB = smem + (RB) * 9216 + hb;                                  \
      _Pragma("unroll")                                                          \
      for (int tap = 0; tap < 9; ++tap) {                                        \
        const int to = TOFF[tap] * 16;                                           \
        _Pragma("unroll")                                                        \
        for (int nt = 0; nt < 2; ++nt) {                                         \
          f16x8 bf = *(const f16x8*)(hB + nt * 2304 + to);                       \
          _Pragma("unroll")                                                      \
          for (int mt = 0; mt < 4; ++mt)                                         \
            acc[mt][nt] = MFMA16(Ah[tap][mt], bf, acc[mt][nt]);                  \
        }                                                                        \
      }                                                                          \
      const char* xB = smem + XP + (RB) * 1152 + xpb;                            \
      _Pragma("unroll")                                                          \
      for (int nt = 0; nt < 2; ++nt) {                                           \
        const char* base = xB + nt * 288;                                        \
        f16x4 lo = *(const f16x4*)(base + xo0);                                  \
        f16x4 hi = *(const f16x4*)(base + xo1);                                  \
        f16x8 bf1 = __builtin_shufflevector(lo, hi, 0, 1, 2, 3, 4, 5, 6, 7);     \
        f16x4 l8 = *(const f16x4*)(base + 112);                                  \
        f16x8 bf2 = __builtin_shufflevector(l8, l8, 0, 1, 2, 3, 0, 1, 2, 3);     \
        _Pragma("unroll")                                                        \
        for (int mt = 0; mt < 4; ++mt) {                                         \
          acc[mt][nt] = MFMA16(Ax1[mt], bf1, acc[mt][nt]);                       \
          acc[mt][nt] = MFMA16(Ax2[mt], bf2, acc[mt][nt]);                       \
        }                                                                        \
      }                                                                          \
      char* hW = smem + (1 - (RB)) * 9216 + wbase;                               \
      _Pragma("unroll")                                                          \
      for (int mt = 0; mt < 4; ++mt) {                                           \
        _Pragma("unroll")                                                        \
        for (int nt = 0; nt < 2; ++nt) {                                         \
          float ig = sigm(acc[mt][nt][0]);                                       \
          float fg = sigm(acc[mt][nt][1]);                                       \
          float og = sigm(acc[mt][nt][2]);                                       \
          float gg = tanh_(acc[mt][nt][3]);                                      \
          float cn = fg * cst[mt][nt] + ig * gg;                                 \
          cst[mt][nt] = cn;                                                      \
          f16 h = (f16)(og * tanh_(cn));                                         \
          if (t < 11) {                                                          \
            *(f16*)(hW + nt * 2304 + (mt >> 1) * 576 + (mt & 1) * 8) = h;        \
          } else {                                                               \
            int ch = mg * 16 + mt * 4 + lk;                                      \
            wz[(size_t)(bg + ng * 2 + nt) * 544 + ch * 16 + lr] = h;             \
          }                                                                      \
        }                                                                        \
      }                                                                          \
      if (t < 11) {                                                              \
        if (stg) *(f16*)(smem + (1 - (RB)) * 1152 + xdst) = (f16)xv;             \
      } else if (tid < 128) {                                                    \
        int b = tid >> 5, k2 = tid & 31;                                         \
        float h0 = ghour[bg + b];                                                \
        float a = ghb2[k2];                                                      \
        _Pragma("unroll")                                                        \
        for (int ii = 0; ii < 16; ++ii) {                                        \
          float u = fmaxf(h0 * ghw1[ii] + ghb1[ii], 0.0f);                       \
          a += u * ghw2[ii * 32 + k2];                                           \
        }                                                                        \
        wz[(size_t)(bg + b) * 544 + 512 + k2] = (f16)a;                          \
      }                                                                          \
      __syncthreads();                                                           \
    }

    for (int tb = 0; tb < 12; tb += 2) {
      STEP(tb, 0)
      STEP(tb + 1, 1)
    }
#undef STEP
  }
}

// ======================= prep: weight transpose fp32->f16 =======================
extern "C" __global__ void hwq_prep(const float* __restrict__ gdw1,
                                    const float* __restrict__ gdw2,
                                    const float* __restrict__ gdw3,
                                    f16* __restrict__ w1t, f16* __restrict__ w2t,
                                    f16* __restrict__ w3t)
{
  int i0 = blockIdx.x * 256 + threadIdx.x;
  int stride = gridDim.x * 256;
  for (int idx = i0; idx < 139264; idx += stride) {
    int n = idx / 544, k = idx - n * 544;
    w1t[idx] = (f16)gdw1[k * 256 + n];
  }
  for (int idx = i0; idx < 32768; idx += stride) {
    int n = idx >> 8, k = idx & 255;
    w2t[idx] = (f16)gdw2[k * 128 + n];
  }
  for (int idx = i0; idx < 4096; idx += stride) {
    int n = idx >> 7, k = idx & 127;
    w3t[idx] = (n < 30) ? (f16)gdw3[k * 30 + n] : (f16)0.0f;
  }
}

// ======================= Kernel B: decoder MLP =======================
extern "C" __global__ __launch_bounds__(256, 2)
void hwq_dec(const f16* __restrict__ wz, const f16* __restrict__ w1t,
             const f16* __restrict__ w2t, const f16* __restrict__ w3t,
             const float* __restrict__ gdb1, const float* __restrict__ gdb2,
             const float* __restrict__ gdb3, float* __restrict__ gout)
{
  __shared__ __align__(16) char smem[55296];
  f16* a1 = (f16*)smem;               // [64][280]
  f16* a2 = (f16*)(smem + 35840);     // [64][152]
  const int tid = threadIdx.x;
  const int lane = tid & 63;
  const int wv = tid >> 6;
  const int lr = lane & 15;
  const int lk = lane >> 4;
  const int s0 = blockIdx.x << 6;

  f32x4 acc1[4][4];
  #pragma unroll
  for (int nt = 0; nt < 4; ++nt) {
    float bb = gdb1[wv * 64 + nt * 16 + lr];
    f32x4 bv = {bb, bb, bb, bb};
    #pragma unroll
    for (int mt = 0; mt < 4; ++mt) acc1[mt][nt] = bv;
  }
  for (int kt = 0; kt < 17; ++kt) {
    f16x8 af[4];
    #pragma unroll
    for (int mt = 0; mt < 4; ++mt)
      af[mt] = *(const f16x8*)(wz + (size_t)(s0 + mt * 16 + lr) * 544 + kt * 32 + lk * 8);
    #pragma unroll
    for (int nt = 0; nt < 4; ++nt) {
      f16x8 bf = *(const f16x8*)(w1t + (size_t)(wv * 64 + nt * 16 + lr) * 544 + kt * 32 + lk * 8);
      #pragma unroll
      for (int mt = 0; mt < 4; ++mt)
        acc1[mt][nt] = MFMA16(af[mt], bf, acc1[mt][nt]);
    }
  }
  #pragma unroll
  for (int mt = 0; mt < 4; ++mt)
    #pragma unroll
    for (int nt = 0; nt < 4; ++nt) {
      int n = wv * 64 + nt * 16 + lr;
      #pragma unroll
      for (int r = 0; r < 4; ++r)
        a1[(mt * 16 + lk * 4 + r) * 280 + n] = (f16)fmaxf(acc1[mt][nt][r], 0.0f);
    }
  __syncthreads();

  f32x4 acc2[4][2];
  #pragma unroll
  for (int nt = 0; nt < 2; ++nt) {
    float bb = gdb2[wv * 32 + nt * 16 + lr];
    f32x4 bv = {bb, bb, bb, bb};
    #pragma unroll
    for (int mt = 0; mt < 4; ++mt) acc2[mt][nt] = bv;
  }
  for (int kt = 0; kt < 8; ++kt) {
    f16x8 af[4];
    #pragma unroll
    for (int mt = 0; mt < 4; ++mt)
      af[mt] = *(const f16x8*)(a1 + (mt * 16 + lr) * 280 + kt * 32 + lk * 8);
    #pragma unroll
    for (int nt = 0; nt < 2; ++nt) {
      f16x8 bf = *(const f16x8*)(w2t + (size_t)(wv * 32 + nt * 16 + lr) * 256 + kt * 32 + lk * 8);
      #pragma unroll
      for (int mt = 0; mt < 4; ++mt)
        acc2[mt][nt] = MFMA16(af[mt], bf, acc2[mt][nt]);
    }
  }
  __syncthreads();
  #pragma unroll
  for (int mt = 0; mt < 4; ++mt)
    #pragma unroll
    for (int nt = 0; nt < 2; ++nt) {
      int n = wv * 32 + nt * 16 + lr;
      #pragma unroll
      for (int r = 0; r < 4; ++r)
        a2[(mt * 16 + lk * 4 + r) * 152 + n] = (f16)fmaxf(acc2[mt][nt][r], 0.0f);
    }
  __syncthreads();

  if (wv < 2) {
    int n = wv * 16 + lr;
    float bb = (n < 30) ? gdb3[n] : 0.0f;
    f32x4 acc3[4];
    #pragma unroll
    for (int mt = 0; mt < 4; ++mt) { f32x4 bv = {bb, bb, bb, bb}; acc3[mt] = bv; }
    #pragma unroll
    for (int kt = 0; kt < 4; ++kt) {
      f16x8 bf = *(const f16x8*)(w3t + n * 128 + kt * 32 + lk * 8);
      #pragma unroll
      for (int mt = 0; mt < 4; ++mt) {
        f16x8 af = *(const f16x8*)(a2 + (mt * 16 + lr) * 152 + kt * 32 + lk * 8);
        acc3[mt] = MFMA16(af, bf, acc3[mt]);
      }
    }
    if (n < 30) {
      #pragma unroll
      for (int mt = 0; mt < 4; ++mt)
        #pragma unroll
        for (int r = 0; r < 4; ++r)
          gout[(size_t)(s0 + mt * 16 + lk * 4 + r) * 30 + n] = sigm(acc3[mt][r]);
    }
  }
}

// ======================= Fallback: monolithic kernel (R1) =======================
typedef _Float16 f16x4m __attribute__((ext_vector_type(4)));
#define OFF_B 46080
#define SMEM_BYTES (46080 + 17408)

extern "C" __global__ __launch_bounds__(256, 1)
void hwq_fused_mono(const float* __restrict__ gx, const float* __restrict__ ghour,
               const float* __restrict__ gcw, const float* __restrict__ gcb,
               const float* __restrict__ ghw1, const float* __restrict__ ghb1,
               const float* __restrict__ ghw2, const float* __restrict__ ghb2,
               const float* __restrict__ gdw1, const float* __restrict__ gdb1,
               const float* __restrict__ gdw2, const float* __restrict__ gdb2,
               const float* __restrict__ gdw3, const float* __restrict__ gdb3,
               float* __restrict__ gout)
{
  __shared__ __align__(16) char smem[SMEM_BYTES];
  const int tid = threadIdx.x;
  const int lane = tid & 63;
  const int wv = tid >> 6;
  const int mg = wv & 1;
  const int ng = wv >> 1;
  const int lr = lane & 15;
  const int lk = lane >> 4;
  const int bg = blockIdx.x << 4;

  f16x8 Ah[9][4];
  {
    f16* wst = (f16*)(smem);
    #pragma unroll
    for (int c = 0; c < 2; ++c) {
      __syncthreads();
      for (int i = tid; i < 18432; i += 256) {
        int oc = i / 288, rem = i - oc * 288;
        wst[i] = (f16)gcw[(c * 64 + oc) * 315 + 27 + rem];
      }
      __syncthreads();
      #pragma unroll
      for (int g = 0; g < 2; ++g) {
        int ocl = g * 32 + mg * 16 + lr;
        #pragma unroll
        for (int tap = 0; tap < 9; ++tap) {
          f16x8 f;
          #pragma unroll
          for (int j = 0; j < 8; ++j)
            f[j] = wst[ocl * 288 + (lk * 8 + j) * 9 + tap];
          Ah[tap][c * 2 + g] = f;
        }
      }
    }
  }
  f16x8 Ax[4];
  {
    f16* xw = (f16*)(smem + OFF_B);
    __syncthreads();
    for (int i = tid; i < 3456; i += 256) {
      int oc = i / 27, rem = i - oc * 27;
      xw[i] = (f16)gcw[oc * 315 + rem];
    }
    __syncthreads();
    #pragma unroll
    for (int mt = 0; mt < 4; ++mt) {
      int oc = mt * 32 + mg * 16 + lr;
      f16x8 f;
      #pragma unroll
      for (int j = 0; j < 8; ++j) {
        int k = lk * 8 + j;
        int tap = (k * 11) >> 5;
        int ic = k - 3 * tap;
        f16 v = (f16)0.0f;
        if (k < 27) v = xw[oc * 27 + ic * 9 + tap];
        f[j] = v;
      }
      Ax[mt] = f;
    }
    __syncthreads();
  }

  float bias[4][4];
  #pragma unroll
  for (int mt = 0; mt < 4; ++mt)
    #pragma unroll
    for (int r = 0; r < 4; ++r)
      bias[mt][r] = gcb[mt * 32 + mg * 16 + lk * 4 + r];

  {
    float* za = (float*)smem;
    for (int i = tid; i < 11520; i += 256) za[i] = 0.0f;
    float* zb = (float*)(smem + OFF_B);
    for (int i = tid; i < 1152; i += 256) zb[i] = 0.0f;
    __syncthreads();
    for (int i = tid; i < 768; i += 256) {
      int b = i / 48, rem = i - b * 48;
      int pos = rem & 15;
      int ic = rem >> 4;
      int pp = (pos >> 2) * 6 + (pos & 3) + 7;
      *(f16*)(smem + OFF_B + b * 288 + pp * 8 + ic * 2) =
          (f16)gx[(size_t)(bg + b) * 576 + rem];
    }
    __syncthreads();
  }

  int hbase[8], xbase[8], wbase[8];
  #pragma unroll
  for (int nt = 0; nt < 8; ++nt) {
    int n = ng * 128 + nt * 16 + lr;
    int b = n >> 4, pos = n & 15;
    int pp0 = (pos >> 2) * 6 + (pos & 3);
    hbase[nt] = b * 2880 + pp0 * 80 + lk * 16;
    xbase[nt] = OFF_B + b * 288 + pp0 * 8;
    wbase[nt] = b * 2880 + (pp0 + 7) * 80 + (mg * 16 + lk * 4) * 2;
  }
  int xoff[8], xval[8];
  #pragma unroll
  for (int j = 0; j < 8; ++j) {
    int k = lk * 8 + j;
    int tap = (k * 11) >> 5;
    int ic = k - 3 * tap;
    xoff[j] = ((tap / 3) * 6 + (tap % 3)) * 8 + ic * 2;
    xval[j] = (k < 27);
  }

  const int TOFF[9] = {0, 1, 2, 6, 7, 8, 12, 13, 14};

  f32x4 cst[8];
  #pragma unroll
  for (int nt = 0; nt < 8; ++nt) { f32x4 z = {0.f, 0.f, 0.f, 0.f}; cst[nt] = z; }

  for (int t = 0; t < 12; ++t) {
    f32x4 acc[4][8];
    #pragma unroll
    for (int mt = 0; mt < 4; ++mt) {
      f32x4 bi = {bias[mt][0], bias[mt][1], bias[mt][2], bias[mt][3]};
      #pragma unroll
      for (int nt = 0; nt < 8; ++nt) acc[mt][nt] = bi;
    }
    #pragma unroll
    for (int tap = 0; tap < 9; ++tap) {
      #pragma unroll
      for (int nt = 0; nt < 8; ++nt) {
        f16x8 bf = *(const f16x8*)(smem + hbase[nt] + TOFF[tap] * 80);
        #pragma unroll
        for (int mt = 0; mt < 4; ++mt)
          acc[mt][nt] = MFMA16(Ah[tap][mt], bf, acc[mt][nt]);
      }
    }
    #pragma unroll
    for (int nt = 0; nt < 8; ++nt) {
      f16x8 bf;
      #pragma unroll
      for (int j = 0; j < 8; ++j) {
        int a = xval[j] ? (xbase[nt] + xoff[j]) : OFF_B;
        bf[j] = *(const f16*)(smem + a);
      }
      #pragma unroll
      for (int mt = 0; mt < 4; ++mt)
        acc[mt][nt] = MFMA16(Ax[mt], bf, acc[mt][nt]);
    }
    __syncthreads();

    #pragma unroll
    for (int nt = 0; nt < 8; ++nt) {
      f16 hh[4];
      #pragma unroll
      for (int r = 0; r < 4; ++r) {
        float ig = sigm(acc[0][nt][r]);
        float fg = sigm(acc[1][nt][r]);
        float og = sigm(acc[2][nt][r]);
        float gg = tanh_(acc[3][nt][r]);
        float cn = fg * cst[nt][r] + ig * gg;
        cst[nt][r] = cn;
        hh[r] = (f16)(og * tanh_(cn));
      }
      if (t < 11) {
        f16x4m hv = {hh[0], hh[1], hh[2], hh[3]};
        *(f16x4m*)(smem + wbase[nt]) = hv;
      } else {
        int n = ng * 128 + nt * 16 + lr;
        int b = n >> 4, pos = n & 15;
        int ch0 = mg * 16 + lk * 4;
        #pragma unroll
        for (int r = 0; r < 4; ++r)
          *(f16*)(smem + OFF_B + b * 1088 + (ch0 + r) * 32 + pos * 2) = hh[r];
      }
    }
    if (t < 11) {
      for (int i = tid; i < 768; i += 256) {
        int b = i / 48, rem = i - b * 48;
        int pos = rem & 15;
        int ic = rem >> 4;
        int pp = (pos >> 2) * 6 + (pos & 3) + 7;
        *(f16*)(smem + OFF_B + b * 288 + pp * 8 + ic * 2) =
            (f16)gx[(size_t)(bg + b) * 576 + (t + 1) * 48 + rem];
      }
    } else {
      for (int i = tid; i < 512; i += 256) {
        int b = i >> 5, k2 = i & 31;
        float h0 = ghour[bg + b];
        float a = ghb2[k2];
        #pragma unroll
        for (int ii = 0; ii < 16; ++ii) {
          float u = fmaxf(h0 * ghw1[ii] + ghb1[ii], 0.0f);
          a += u * ghw2[ii * 32 + k2];
        }
        *(f16*)(smem + OFF_B + b * 1088 + (512 + k2) * 2) = (f16)a;
      }
    }
    __syncthreads();
  }

  f16* zz  = (f16*)(smem + OFF_B);
  f16* wch = (f16*)(smem);
  f16* a1  = (f16*)(smem + 16384);
  f16* a2  = (f16*)(smem + 24576);
  f16* w3s = (f16*)(smem + 28672);

  f32x4 acc1[4];
  #pragma unroll
  for (int i = 0; i < 4; ++i) { f32x4 z = {0.f, 0.f, 0.f, 0.f}; acc1[i] = z; }
  for (int kt = 0; kt < 17; ++kt) {
    __syncthreads();
    for (int i = tid; i < 8192; i += 256) {
      int k = i >> 8, n = i & 255;
      wch[i] = (f16)gdw1[(kt * 32 + k) * 256 + n];
    }
    __syncthreads();
    f16x8 af = *(const f16x8*)((char*)zz + lr * 1088 + (kt * 32 + lk * 8) * 2);
    #pragma unroll
    for (int nt = 0; nt < 4; ++nt) {
      int n = (wv * 4 + nt) * 16 + lr;
      f16x8 bf;
      #pragma unroll
      for (int j = 0; j < 8; ++j) bf[j] = wch[(lk * 8 + j) * 256 + n];
      acc1[nt] = MFMA16(af, bf, acc1[nt]);
    }
  }
  __syncthreads();
  #pragma unroll
  for (int nt = 0; nt < 4; ++nt) {
    int n = (wv * 4 + nt) * 16 + lr;
    float bb = gdb1[n];
    #pragma unroll
    for (int r = 0; r < 4; ++r)
      a1[(lk * 4 + r) * 256 + n] = (f16)fmaxf(acc1[nt][r] + bb, 0.0f);
  }

  f32x4 acc2[2];
  #pragma unroll
  for (int i = 0; i < 2; ++i) { f32x4 z = {0.f, 0.f, 0.f, 0.f}; acc2[i] = z; }
  for (int kt = 0; kt < 8; ++kt) {
    __syncthreads();
    for (int i = tid; i < 4096; i += 256) {
      int k = i >> 7, n = i & 127;
      wch[i] = (f16)gdw2[(kt * 32 + k) * 128 + n];
    }
    __syncthreads();
    f16x8 af = *(const f16x8*)((char*)a1 + lr * 512 + (kt * 32 + lk * 8) * 2);
    #pragma unroll
    for (int nt = 0; nt < 2; ++nt) {
      int n = (wv * 2 + nt) * 16 + lr;
      f16x8 bf;
      #pragma unroll
      for (int j = 0; j < 8; ++j) bf[j] = wch[(lk * 8 + j) * 128 + n];
      acc2[nt] = MFMA16(af, bf, acc2[nt]);
    }
  }
  __syncthreads();
  #pragma unroll
  for (int nt = 0; nt < 2; ++nt) {
    int n = (wv * 2 + nt) * 16 + lr;
    float bb = gdb2[n];
    #pragma unroll
    for (int r = 0; r < 4; ++r)
      a2[(lk * 4 + r) * 128 + n] = (f16)fmaxf(acc2[nt][r] + bb, 0.0f);
  }
  __syncthreads();

  for (int i = tid; i < 4096; i += 256) {
    int k = i >> 5, n = i & 31;
    w3s[i] = (n < 30) ? (f16)gdw3[k * 30 + n] : (f16)0.0f;
  }
  __syncthreads();
  if (wv < 2) {
    f32x4 acc3 = {0.f, 0.f, 0.f, 0.f};
    int n = wv * 16 + lr;
    #pragma unroll
    for (int kt = 0; kt < 4; ++kt) {
      f16x8 af = *(const f16x8*)((char*)a2 + lr * 256 + (kt * 32 + lk * 8) * 2);
      f16x8 bf;
      #pragma unroll
      for (int j = 0; j < 8; ++j) bf[j] = w3s[(kt * 32 + lk * 8 + j) * 32 + n];
      acc3 = MFMA16(af, bf, acc3);
    }
    if (n < 30) {
      float bb = gdb3[n];
      #pragma unroll
      for (int r = 0; r < 4; ++r) {
        float v = sigm(acc3[r] + bb);
        gout[(size_t)(bg + lk * 4 + r) * 30 + n] = v;
      }
    }
  }
}

extern "C" void kernel_launch(void* const* d_in, const int* in_sizes, int n_in,
                              void* d_out, int out_size, void* d_ws, size_t ws_size,
                              hipStream_t stream) {
  (void)in_sizes; (void)n_in; (void)out_size;
  const size_t W1OFF = 35651584;             // z: 32768*544*2
  const size_t W2OFF = W1OFF + 278528;       // w1t
  const size_t W3OFF = W2OFF + 65536;        // w2t
  const size_t NEED  = W3OFF + 8192;         // w3t
  if (ws_size >= NEED) {
    f16* wzp = (f16*)d_ws;
    f16* w1t = (f16*)((char*)d_ws + W1OFF);
    f16* w2t = (f16*)((char*)d_ws + W2OFF);
    f16* w3t = (f16*)((char*)d_ws + W3OFF);
    hwq_prep<<<256, 256, 0, stream>>>((const float*)d_in[8], (const float*)d_in[10],
                                      (const float*)d_in[12], w1t, w2t, w3t);
    hwq_rec<<<GRID_REC, 256, 0, stream>>>(
        (const float*)d_in[0], (const float*)d_in[1], (const float*)d_in[2],
        (const float*)d_in[3], (const float*)d_in[4], (const float*)d_in[5],
        (const float*)d_in[6], (const float*)d_in[7], wzp);
    hwq_dec<<<512, 256, 0, stream>>>(wzp, w1t, w2t, w3t,
                                     (const float*)d_in[9], (const float*)d_in[11],
                                     (const float*)d_in[13], (float*)d_out);
  } else {
    hwq_fused_mono<<<2048, 256, 0, stream>>>(
        (const float*)d_in[0],  (const float*)d_in[1],  (const float*)d_in[2],
        (const float*)d_in[3],  (const float*)d_in[4],  (const float*)d_in[5],
        (const float*)d_in[6],  (const float*)d_in[7],  (const float*)d_in[8],
        (const float*)d_in[9],  (const float*)d_in[10], (const float*)d_in[11],
        (const float*)d_in[12], (const float*)d_in[13], (float*)d_out);
  }
}